// Round 4
// baseline (165.341 us; speedup 1.0000x reference)
//
#include <hip/hip_runtime.h>
#include <math.h>

// Ising-style flip: out = s * flip where
//   Js = up+down+left+right (periodic, r=1); de = (2*s)*Js
//   p  = de<=0 ? 1 : exp(-de); flip = (rand<p)&&(drop>0.5) ? -1 : +1
// x, rand: (16,1,2048,2048) f32; drop: (2048,2048) f32.
//
// R4: 8 rows per thread in two rolling 4-row phases (x refetch 1.25x, fewer
// VMEM ops per byte, ~2x per-wave ILP). Keeps XCD swizzle, shuffle halos,
// NT rand loads, NT stores.

namespace {

constexpr int Bn  = 16;
constexpr int Hn  = 2048;
constexpr int Wn  = 2048;
constexpr int W4  = Wn / 4;             // 512 float4 per row
constexpr int RPT = 8;                  // rows per thread
constexpr int HS  = Hn / RPT;           // 256 strips per image
constexpr int NTHREADS = Bn * HS * W4;  // 2,097,152
constexpr int NBLK = NTHREADS / 256;    // 8,192
constexpr int NXCD = 8;
constexpr int BLK_PER_XCD = NBLK / NXCD; // 1024

typedef float f4 __attribute__((ext_vector_type(4)));

__device__ __forceinline__ f4 flip_row(const f4 up, const f4 sc, const f4 dn,
                                       const f4 rv, const f4 dv,
                                       const float lf, const float rt)
{
    f4 o;
#pragma unroll
    for (int j = 0; j < 4; ++j) {
        const float s     = sc[j];
        const float left  = (j == 0) ? lf : sc[j - 1];
        const float right = (j == 3) ? rt : sc[j + 1];
        // Reference op order: Js = ((up+down)+left)+right; de = (2*s)*Js
        const float js = ((up[j] + dn[j]) + left) + right;
        const float de = (2.0f * s) * js;

        bool lt;
        if (de <= 0.0f) {
            lt = true;                    // p = 1; rand in [0,1) < 1
        } else {
            float p = expf(-de);
            // Tie band: near-equal rand vs p -> recompute exp in double to
            // match the host reference's correctly-rounded flip decision.
            if (fabsf(rv[j] - p) <= p * 1.0e-6f) {
                p = (float)exp(-(double)de);
            }
            lt = rv[j] < p;
        }
        const bool flip = lt && (dv[j] > 0.5f);
        o[j] = flip ? -s : s;
    }
    return o;
}

__global__ __launch_bounds__(256) void ising_flip_kernel(
    const float* __restrict__ x,
    const float* __restrict__ rnd,
    const float* __restrict__ drop,
    float* __restrict__ out)
{
    // XCD swizzle: physical block b lands on XCD b%8 (round-robin dispatch).
    const int phys    = blockIdx.x;
    const int logical = (phys & (NXCD - 1)) * BLK_PER_XCD + (phys >> 3);
    const int tid     = logical * 256 + (int)threadIdx.x;
    const int lane    = (int)threadIdx.x & 63;

    const int wv = tid & (W4 - 1);          // col-vec, fastest (coalesced)
    const int hs = (tid >> 9) & (HS - 1);   // row strip
    const int b  = tid >> 17;               // image

    const int    c0  = wv * 4;
    const int    h0  = hs * RPT;
    const size_t img = (size_t)b * (size_t)(Hn * Wn);
    const float* xi  = x + img;

    const int cl = (c0 == 0)      ? (Wn - 1) : (c0 - 1);
    const int cr = (c0 + 4 == Wn) ? 0        : (c0 + 4);

    // ---- Phase A: rows h0..h0+3 (x rows h0-1..h0+4) ----
    f4 a[6];
#pragma unroll
    for (int k = 0; k < 6; ++k) {
        int hr = h0 - 1 + k;
        hr = (hr < 0) ? (Hn - 1) : hr;          // only k=0 can wrap
        a[k] = *(const f4*)(xi + (size_t)hr * Wn + c0);
    }
    f4 rvA[4], dvA[4];
#pragma unroll
    for (int i = 0; i < 4; ++i) {
        const int row = (h0 + i) * Wn;
        rvA[i] = __builtin_nontemporal_load((const f4*)(rnd + img + row + c0));
        dvA[i] = *(const f4*)(drop + row + c0);
    }
    float lfA[4], rtA[4];
#pragma unroll
    for (int i = 0; i < 4; ++i) {
        lfA[i] = __shfl_up(a[i + 1][3], 1);
        rtA[i] = __shfl_down(a[i + 1][0], 1);
    }
    if (lane == 0) {
#pragma unroll
        for (int i = 0; i < 4; ++i) lfA[i] = xi[(h0 + i) * Wn + cl];
    }
    if (lane == 63) {
#pragma unroll
        for (int i = 0; i < 4; ++i) rtA[i] = xi[(h0 + i) * Wn + cr];
    }
#pragma unroll
    for (int i = 0; i < 4; ++i) {
        const f4 o = flip_row(a[i], a[i + 1], a[i + 2], rvA[i], dvA[i],
                              lfA[i], rtA[i]);
        __builtin_nontemporal_store(o, (f4*)(out + img + (size_t)(h0 + i) * Wn + c0));
    }

    // ---- Phase B: rows h0+4..h0+7 (new x rows h0+5..h0+8; reuse a[4],a[5]) ----
    f4 bx[4];
#pragma unroll
    for (int k = 0; k < 4; ++k) {
        int hr = h0 + 5 + k;
        hr = (hr >= Hn) ? 0 : hr;               // only k=3 can wrap
        bx[k] = *(const f4*)(xi + (size_t)hr * Wn + c0);
    }
    f4 rvB[4], dvB[4];
#pragma unroll
    for (int i = 0; i < 4; ++i) {
        const int row = (h0 + 4 + i) * Wn;
        rvB[i] = __builtin_nontemporal_load((const f4*)(rnd + img + row + c0));
        dvB[i] = *(const f4*)(drop + row + c0);
    }
    // cur rows for phase B: {a[5], bx[0], bx[1], bx[2]}
    const f4 curB0 = a[5], curB1 = bx[0], curB2 = bx[1], curB3 = bx[2];
    const f4 upB0  = a[4], upB1  = a[5], upB2  = bx[0], upB3 = bx[1];
    const f4 dnB0  = bx[0], dnB1 = bx[1], dnB2 = bx[2], dnB3 = bx[3];
    const f4 curB[4] = {curB0, curB1, curB2, curB3};
    const f4 upBv[4] = {upB0, upB1, upB2, upB3};
    const f4 dnBv[4] = {dnB0, dnB1, dnB2, dnB3};

    float lfB[4], rtB[4];
#pragma unroll
    for (int i = 0; i < 4; ++i) {
        lfB[i] = __shfl_up(curB[i][3], 1);
        rtB[i] = __shfl_down(curB[i][0], 1);
    }
    if (lane == 0) {
#pragma unroll
        for (int i = 0; i < 4; ++i) lfB[i] = xi[(h0 + 4 + i) * Wn + cl];
    }
    if (lane == 63) {
#pragma unroll
        for (int i = 0; i < 4; ++i) rtB[i] = xi[(h0 + 4 + i) * Wn + cr];
    }
#pragma unroll
    for (int i = 0; i < 4; ++i) {
        const f4 o = flip_row(upBv[i], curB[i], dnBv[i], rvB[i], dvB[i],
                              lfB[i], rtB[i]);
        __builtin_nontemporal_store(o, (f4*)(out + img + (size_t)(h0 + 4 + i) * Wn + c0));
    }
}

} // namespace

extern "C" void kernel_launch(void* const* d_in, const int* in_sizes, int n_in,
                              void* d_out, int out_size, void* d_ws, size_t ws_size,
                              hipStream_t stream)
{
    const float* x    = (const float*)d_in[0];
    const float* rnd  = (const float*)d_in[1];
    const float* drop = (const float*)d_in[2];
    float* out        = (float*)d_out;

    hipLaunchKernelGGL(ising_flip_kernel, dim3(NBLK), dim3(256), 0, stream,
                       x, rnd, drop, out);
}